// Round 6
// baseline (347.192 us; speedup 1.0000x reference)
//
#include <hip/hip_runtime.h>

// NCC loss: 1 - mean( cross^2 / (pvar*tvar + 1e-8) ) over 9^3 zero-padded
// box windows, input (4,1,160,160,160) fp32.
//
// R6: wave specialization. R5's wave 0 carried staging AND the whole y+cc
// pass -> waves 1-2 idled at each barrier. Now BLK=256: wave 0 is a pure
// compute wave (y+cc, 4 voxels/lane), waves 1-3 stage (144 active lanes:
// register slice-ring fold + prefetch + DPP x-pass). Warm-up issues all 16
// float4 loads before folding (one waitcnt, not 8 dependent chains).
// Proven pieces kept: register 9-slot ring (static slots, 9-periodic unroll),
// DPP x 9-sum, s2 [f][y][x] stride-20 (0 bank conflicts), double buffer,
// ONE barrier per z-step.

#define DSZ    160
#define NBATCH 4
#define RAD    4
#define TX     16
#define TY     16
#define ZCHUNK 40
#define SLICE  (DSZ*DSZ)
#define VOL    (DSZ*DSZ*DSZ)
#define WINV   (1.0f/729.0f)
#define NVOX_INV (1.0f/16384000.0f)

#define NROW 24        // halo rows per tile
#define NGRP 6         // x groups of 4 halo cols (24)
#define BLK  256

#define S2_RS 20                 // row stride: 16 outputs + pad (2-way banks)
#define S2_FS (NROW*S2_RS)       // 480 floats per field
#define S2_BUF (5*S2_FS)         // 2400 floats per parity buffer

__device__ __forceinline__ float dpp_shl1(float x) {  // lane i <- lane i+1 (16-lane row, OOB=0)
    return __int_as_float(__builtin_amdgcn_update_dpp(0, __float_as_int(x), 0x101, 0xf, 0xf, true));
}
__device__ __forceinline__ float dpp_shl2(float x) {  // lane i <- lane i+2
    return __int_as_float(__builtin_amdgcn_update_dpp(0, __float_as_int(x), 0x102, 0xf, 0xf, true));
}

__global__ __launch_bounds__(BLK, 4)
void ncc_main(const float* __restrict__ pred, const float* __restrict__ tgt,
              float* __restrict__ accum)
{
    const int tid = threadIdx.x;
    // staging mapping (waves 1-3): st = tid-64 in [0,192), 24 rows x 8 lanes
    const int st  = tid - 64;
    const int row = st >> 3;
    const int g   = st & 7;
    const bool stg = (tid >= 64) && (g < NGRP);

    const int ox  = blockIdx.x * TX;
    const int oy  = blockIdx.y * TY;
    const int batch = blockIdx.z >> 2;
    const int z0  = (blockIdx.z & 3) * ZCHUNK;

    __shared__ float s2[2*S2_BUF];   // 19.2 KB, double-buffered [f][y][x pad20]

    const int  gy  = oy - RAD + row;
    const int  gx0 = ox - RAD + g*4;
    const bool ldok = stg && (gy >= 0) && (gy < DSZ) && (gx0 >= 0) && (gx0 + 3 < DSZ);
    const int  base = batch*VOL + gy*DSZ + gx0;     // only used under ldok

    // register ring of raw slice values (own 4 columns), chunk-local slots
    float rp[9][4], rt[9][4];
    float zs[5][4];
    #pragma unroll
    for (int k = 0; k < 9; ++k)
        #pragma unroll
        for (int j = 0; j < 4; ++j) { rp[k][j] = 0.f; rt[k][j] = 0.f; }
    #pragma unroll
    for (int f = 0; f < 5; ++f)
        #pragma unroll
        for (int j = 0; j < 4; ++j) zs[f][j] = 0.f;

    // ---- warm-up: issue ALL 16 loads (slices z0-4..z0+3 -> slots 0..7),
    // then fold. Loads are independent -> single waitcnt drain.
    #pragma unroll
    for (int i = 0; i < 8; ++i) {
        int z = z0 - RAD + i;               // always < DSZ here
        if (ldok && z >= 0) {
            float4 p4 = *(const float4*)(pred + base + z*SLICE);
            float4 t4 = *(const float4*)(tgt  + base + z*SLICE);
            rp[i][0]=p4.x; rp[i][1]=p4.y; rp[i][2]=p4.z; rp[i][3]=p4.w;
            rt[i][0]=t4.x; rt[i][1]=t4.y; rt[i][2]=t4.z; rt[i][3]=t4.w;
        }
    }
    #pragma unroll
    for (int i = 0; i < 8; ++i)
        #pragma unroll
        for (int j = 0; j < 4; ++j) {
            float p = rp[i][j], t = rt[i][j];
            zs[0][j] += p;   zs[1][j] += t;
            zs[2][j] += p*p; zs[3][j] += t*t;
            zs[4][j] += p*t;
        }

    // ---- streaming prefetch of the next add-slice ----
    int za = z0 + RAD;                      // absolute z of next fetch
    int zmax = z0 + ZCHUNK + RAD;           // last useful slice + 1
    if (zmax > DSZ) zmax = DSZ;
    float4 pa4 = {0,0,0,0}, ta4 = {0,0,0,0};
    auto pf = [&]() {
        float4 p = {0,0,0,0}, t = {0,0,0,0};
        if (ldok && za < zmax) {
            p = *(const float4*)(pred + base + za*SLICE);
            t = *(const float4*)(tgt  + base + za*SLICE);
        }
        pa4 = p; ta4 = t; ++za;
    };
    pf();

    int pb = 1;          // parity buffer toggle (first step -> 0)
    float acc = 0.f;

#define NCC_STEP(SLOT) do {                                                   \
    pb ^= 1;                                                                  \
    float* s2w = s2 + pb*S2_BUF;                                              \
    if (stg) {                                                                \
        float pc[4] = {pa4.x,pa4.y,pa4.z,pa4.w};                              \
        float tc[4] = {ta4.x,ta4.y,ta4.z,ta4.w};                              \
        _Pragma("unroll")                                                     \
        for (int j = 0; j < 4; ++j) {                                         \
            float ps = rp[SLOT][j], qs = rt[SLOT][j];                         \
            float d0 = pc[j] - ps, d1 = tc[j] - qs;                           \
            zs[0][j] += d0;                                                   \
            zs[1][j] += d1;                                                   \
            zs[2][j] += d0*(pc[j] + ps);                                      \
            zs[3][j] += d1*(tc[j] + qs);                                      \
            zs[4][j] += pc[j]*tc[j] - ps*qs;                                  \
            rp[SLOT][j] = pc[j];  rt[SLOT][j] = tc[j];                        \
        }                                                                     \
        pf();   /* issue next slice's loads; drain behind the barrier */      \
        _Pragma("unroll")                                                     \
        for (int f = 0; f < 5; ++f) {                                         \
            float P0 = zs[f][0];                                              \
            float P1 = P0 + zs[f][1];                                         \
            float P2 = P1 + zs[f][2];                                         \
            float P3 = P2 + zs[f][3];                                         \
            float T  = dpp_shl1(P3);                                          \
            float Q0 = dpp_shl2(P0), Q1 = dpp_shl2(P1);                       \
            float Q2 = dpp_shl2(P2), Q3 = dpp_shl2(P3);                       \
            if (g < 4) {                                                      \
                float b = P3 + T;                                             \
                float* dst = &s2w[f*S2_FS + row*S2_RS + g*4];                 \
                dst[0] = b + Q0;                                              \
                dst[1] = b - P0 + Q1;                                         \
                dst[2] = b - P1 + Q2;                                         \
                dst[3] = b - P2 + Q3;                                         \
            }                                                                 \
        }                                                                     \
    }                                                                         \
    __syncthreads();                                                          \
    if (tid < 64) {                                                           \
        const int x = tid & 15, yq = (tid >> 4)*4;                            \
        float S[5][4];                                                        \
        _Pragma("unroll")                                                     \
        for (int f = 0; f < 5; ++f) {                                         \
            const float* col = &s2w[f*S2_FS + x];                             \
            float r0 = col[(yq+0)*S2_RS], r1 = col[(yq+1)*S2_RS];             \
            float r2 = col[(yq+2)*S2_RS], r3 = col[(yq+3)*S2_RS];             \
            float run = r0+r1+r2+r3 + col[(yq+4)*S2_RS] + col[(yq+5)*S2_RS]   \
                      + col[(yq+6)*S2_RS] + col[(yq+7)*S2_RS];                \
            run += col[(yq+8)*S2_RS];        S[f][0] = run;                   \
            run += col[(yq+9)*S2_RS]  - r0;  S[f][1] = run;                   \
            run += col[(yq+10)*S2_RS] - r1;  S[f][2] = run;                   \
            run += col[(yq+11)*S2_RS] - r2;  S[f][3] = run;                   \
        }                                                                     \
        _Pragma("unroll")                                                     \
        for (int i = 0; i < 4; ++i) {                                         \
            float Sp = S[0][i], St = S[1][i];                                 \
            float cross = S[4][i] - Sp*St*WINV;                               \
            float pv    = S[2][i] - Sp*Sp*WINV;                               \
            float tv    = S[3][i] - St*St*WINV;                               \
            acc += cross*cross / (pv*tv + 1e-8f);                             \
        }                                                                     \
    }                                                                         \
} while (0)

    // steps s=0..3: slots (s+8)%9 = 8,0,1,2
    NCC_STEP(8); NCC_STEP(0); NCC_STEP(1); NCC_STEP(2);
    // steps s=4..39: slot sequence (s+8)%9 is 9-periodic: 3,4,5,6,7,8,0,1,2
    for (int it = 0; it < 4; ++it) {
        NCC_STEP(3); NCC_STEP(4); NCC_STEP(5);
        NCC_STEP(6); NCC_STEP(7); NCC_STEP(8);
        NCC_STEP(0); NCC_STEP(1); NCC_STEP(2);
    }
#undef NCC_STEP

    // all cc partials live in wave 0
    if (tid < 64) {
        float v = acc;
        #pragma unroll
        for (int off = 32; off > 0; off >>= 1) v += __shfl_down(v, off, 64);
        if (tid == 0) atomicAdd(accum, v);
    }
}

__global__ void ncc_final(const float* __restrict__ accum, float* __restrict__ out)
{
    out[0] = 1.0f - accum[0] * NVOX_INV;
}

extern "C" void kernel_launch(void* const* d_in, const int* in_sizes, int n_in,
                              void* d_out, int out_size, void* d_ws, size_t ws_size,
                              hipStream_t stream)
{
    const float* pred = (const float*)d_in[0];
    const float* tgt  = (const float*)d_in[1];
    float* out = (float*)d_out;
    float* ws  = (float*)d_ws;

    hipMemsetAsync(ws, 0, sizeof(float), stream);
    dim3 grid(DSZ/TX, DSZ/TY, NBATCH*4);   // 10 x 10 x 16 = 1600 blocks
    ncc_main<<<grid, BLK, 0, stream>>>(pred, tgt, ws);
    ncc_final<<<1, 1, 0, stream>>>(ws, out);
}